// Round 1
// baseline (548.168 us; speedup 1.0000x reference)
//
#include <hip/hip_runtime.h>
#include <math.h>

#define HH 7
#define WW 7
#define CC 512
#define HF 64
#define WF 256
#define NS 49           // HH*WW
#define TILE_PAD 257    // 256 + 1 for bank rotation

// Transpose feats (C, HF*WF) -> ws (HF*WF, C) so channel gathers coalesce.
__global__ __launch_bounds__(256) void transpose_feats(const float* __restrict__ in,
                                                       float* __restrict__ out) {
    __shared__ float tile[32][33];
    const int P = HF * WF;  // 16384
    int p  = blockIdx.x * 32 + threadIdx.x;  // spatial index
    int cb = blockIdx.y * 32;                // channel base
#pragma unroll
    for (int r = 0; r < 32; r += 8)
        tile[threadIdx.y + r][threadIdx.x] = in[(size_t)(cb + threadIdx.y + r) * P + p];
    __syncthreads();
    int c  = cb + threadIdx.x;
    int pb = blockIdx.x * 32;
#pragma unroll
    for (int r = 0; r < 32; r += 8)
        out[(size_t)(pb + threadIdx.y + r) * CC + c] = tile[threadIdx.x][threadIdx.y + r];
}

// One block per box. cellmul/cmul parametrize the feats layout:
//   transposed ws path: cellmul=CC, cmul=1
//   direct feats path : cellmul=1,  cmul=HF*WF   (fallback if ws too small)
__global__ __launch_bounds__(256) void roi_pool(const float* __restrict__ src,
                                                const float* __restrict__ boxes,
                                                const int* __restrict__ ih_p,
                                                const int* __restrict__ iw_p,
                                                float* __restrict__ out,
                                                int cellmul, int cmul) {
    __shared__ int4   s_off[NS];
    __shared__ float4 s_wt[NS];
    __shared__ float  tile[NS * TILE_PAD];

    const int b   = blockIdx.x;
    const int tid = threadIdx.x;

    if (tid < NS) {
        int i = tid / WW;
        int j = tid - i * WW;
        float IW1 = (float)(iw_p[0] - 1);
        float IH1 = (float)(ih_p[0] - 1);
        float xc = boxes[b * 4 + 0];
        float yc = boxes[b * 4 + 1];
        float bw = boxes[b * 4 + 2];
        float bh = boxes[b * 4 + 3];
        float inv_w = 1.0f / IW1;
        float inv_h = 1.0f / IH1;
        float tx = (float)(j - 3) * (1.0f / 3.0f);   // linspace(-1,1,7)
        float ty = (float)(i - 3) * (1.0f / 3.0f);
        float gx = (2.0f * xc - IW1) * inv_w + (bw * inv_w) * tx;
        float gy = (2.0f * yc - IH1) * inv_h + (bh * inv_h) * ty;
        float px = (gx + 1.0f) * 0.5f * (float)(WF - 1);
        float py = (gy + 1.0f) * 0.5f * (float)(HF - 1);

        float x0f = floorf(px), y0f = floorf(py);
        float wx1 = px - x0f, wx0 = 1.0f - wx1;
        float wy1 = py - y0f, wy0 = 1.0f - wy1;
        float x1f = x0f + 1.0f, y1f = y0f + 1.0f;

        bool vx0 = (x0f >= 0.0f) && (x0f <= (float)(WF - 1));
        bool vx1 = (x1f >= 0.0f) && (x1f <= (float)(WF - 1));
        bool vy0 = (y0f >= 0.0f) && (y0f <= (float)(HF - 1));
        bool vy1 = (y1f >= 0.0f) && (y1f <= (float)(HF - 1));

        int xi0 = (int)fminf(fmaxf(x0f, 0.0f), (float)(WF - 1));
        int xi1 = (int)fminf(fmaxf(x1f, 0.0f), (float)(WF - 1));
        int yi0 = (int)fminf(fmaxf(y0f, 0.0f), (float)(HF - 1));
        int yi1 = (int)fminf(fmaxf(y1f, 0.0f), (float)(HF - 1));

        int4 o;
        o.x = (yi0 * WF + xi0) * cellmul;
        o.y = (yi0 * WF + xi1) * cellmul;
        o.z = (yi1 * WF + xi0) * cellmul;
        o.w = (yi1 * WF + xi1) * cellmul;
        float4 w4;
        w4.x = wx0 * wy0 * ((vx0 && vy0) ? 1.0f : 0.0f);
        w4.y = wx1 * wy0 * ((vx1 && vy0) ? 1.0f : 0.0f);
        w4.z = wx0 * wy1 * ((vx0 && vy1) ? 1.0f : 0.0f);
        w4.w = wx1 * wy1 * ((vx1 && vy1) ? 1.0f : 0.0f);
        s_off[tid] = o;
        s_wt[tid]  = w4;
    }
    __syncthreads();

    const size_t outbase = (size_t)b * (CC * NS);

    for (int c0 = 0; c0 < CC; c0 += 256) {
        // ---- compute phase: lane = channel (coalesced reads) ----
        const int cterm = (c0 + tid) * cmul;
#pragma unroll 7
        for (int s = 0; s < NS; ++s) {
            int4   o = s_off[s];
            float4 w = s_wt[s];
            float v = src[o.x + cterm] * w.x + src[o.y + cterm] * w.y +
                      src[o.z + cterm] * w.z + src[o.w + cterm] * w.w;
            tile[s * TILE_PAD + tid] = v;
        }
        __syncthreads();
        // ---- write phase: lane = output order (coalesced writes) ----
        const size_t ob = outbase + (size_t)c0 * NS;
#pragma unroll
        for (int k = tid; k < 256 * NS; k += 256) {
            int cl = k / NS;
            int s  = k - cl * NS;
            out[ob + k] = tile[s * TILE_PAD + cl];
        }
        __syncthreads();
    }
}

extern "C" void kernel_launch(void* const* d_in, const int* in_sizes, int n_in,
                              void* d_out, int out_size, void* d_ws, size_t ws_size,
                              hipStream_t stream) {
    const float* feats = (const float*)d_in[0];
    const float* boxes = (const float*)d_in[1];
    const int*   ih    = (const int*)d_in[2];
    const int*   iw    = (const int*)d_in[3];
    float*       out   = (float*)d_out;
    const int B = in_sizes[1] / 4;

    const size_t need = (size_t)CC * HF * WF * sizeof(float);  // 32 MiB
    if (ws_size >= need) {
        float* tf = (float*)d_ws;
        dim3 tb(32, 8);
        dim3 tg((HF * WF) / 32, CC / 32);
        transpose_feats<<<tg, tb, 0, stream>>>(feats, tf);
        roi_pool<<<B, 256, 0, stream>>>(tf, boxes, ih, iw, out, CC, 1);
    } else {
        roi_pool<<<B, 256, 0, stream>>>(feats, boxes, ih, iw, out, 1, HF * WF);
    }
}

// Round 3
// 536.769 us; speedup vs baseline: 1.0212x; 1.0212x over previous
//
#include <hip/hip_runtime.h>
#include <math.h>

#define HH 7
#define WW 7
#define CC 512
#define HF 64
#define WF 256
#define NS 49            // HH*WW
#define TILE_PAD 260     // multiple of 4 (aligned float4 LDS writes); 260%32==4
#define NE4 ((256 * NS) / 4)   // 3136 float4 outputs per 256-channel chunk

typedef float floatv4 __attribute__((ext_vector_type(4)));  // native vec for NT store

// Transpose feats (C, HF*WF) -> ws (HF*WF, C) so channel gathers coalesce.
__global__ __launch_bounds__(256) void transpose_feats(const float* __restrict__ in,
                                                       float* __restrict__ out) {
    __shared__ float tile[32][33];
    const int P = HF * WF;  // 16384
    int p  = blockIdx.x * 32 + threadIdx.x;  // spatial index
    int cb = blockIdx.y * 32;                // channel base
#pragma unroll
    for (int r = 0; r < 32; r += 8)
        tile[threadIdx.y + r][threadIdx.x] = in[(size_t)(cb + threadIdx.y + r) * P + p];
    __syncthreads();
    int c  = cb + threadIdx.x;
    int pb = blockIdx.x * 32;
#pragma unroll
    for (int r = 0; r < 32; r += 8)
        out[(size_t)(pb + threadIdx.y + r) * CC + c] = tile[threadIdx.x][threadIdx.y + r];
}

__device__ __forceinline__ void box_setup(int s, int b,
                                          const float* __restrict__ boxes,
                                          const int* __restrict__ ih_p,
                                          const int* __restrict__ iw_p,
                                          int4* o_out, float4* w_out) {
    int i = s / WW;
    int j = s - i * WW;
    float IW1 = (float)(iw_p[0] - 1);
    float IH1 = (float)(ih_p[0] - 1);
    float xc = boxes[b * 4 + 0];
    float yc = boxes[b * 4 + 1];
    float bw = boxes[b * 4 + 2];
    float bh = boxes[b * 4 + 3];
    float inv_w = 1.0f / IW1;
    float inv_h = 1.0f / IH1;
    float tx = (float)(j - 3) * (1.0f / 3.0f);   // linspace(-1,1,7)
    float ty = (float)(i - 3) * (1.0f / 3.0f);
    float gx = (2.0f * xc - IW1) * inv_w + (bw * inv_w) * tx;
    float gy = (2.0f * yc - IH1) * inv_h + (bh * inv_h) * ty;
    float px = (gx + 1.0f) * 0.5f * (float)(WF - 1);
    float py = (gy + 1.0f) * 0.5f * (float)(HF - 1);

    float x0f = floorf(px), y0f = floorf(py);
    float wx1 = px - x0f, wx0 = 1.0f - wx1;
    float wy1 = py - y0f, wy0 = 1.0f - wy1;
    float x1f = x0f + 1.0f, y1f = y0f + 1.0f;

    bool vx0 = (x0f >= 0.0f) && (x0f <= (float)(WF - 1));
    bool vx1 = (x1f >= 0.0f) && (x1f <= (float)(WF - 1));
    bool vy0 = (y0f >= 0.0f) && (y0f <= (float)(HF - 1));
    bool vy1 = (y1f >= 0.0f) && (y1f <= (float)(HF - 1));

    int xi0 = (int)fminf(fmaxf(x0f, 0.0f), (float)(WF - 1));
    int xi1 = (int)fminf(fmaxf(x1f, 0.0f), (float)(WF - 1));
    int yi0 = (int)fminf(fmaxf(y0f, 0.0f), (float)(HF - 1));
    int yi1 = (int)fminf(fmaxf(y1f, 0.0f), (float)(HF - 1));

    int4 o;
    o.x = yi0 * WF + xi0;
    o.y = yi0 * WF + xi1;
    o.z = yi1 * WF + xi0;
    o.w = yi1 * WF + xi1;
    float4 w4;
    w4.x = wx0 * wy0 * ((vx0 && vy0) ? 1.0f : 0.0f);
    w4.y = wx1 * wy0 * ((vx1 && vy0) ? 1.0f : 0.0f);
    w4.z = wx0 * wy1 * ((vx0 && vy1) ? 1.0f : 0.0f);
    w4.w = wx1 * wy1 * ((vx1 && vy1) ? 1.0f : 0.0f);
    *o_out = o;
    *w_out = w4;
}

// One block per box. src is transposed feats: (HF*WF, CC), channel-contiguous.
__global__ __launch_bounds__(256) void roi_pool_v2(const float* __restrict__ src,
                                                   const float* __restrict__ boxes,
                                                   const int* __restrict__ ih_p,
                                                   const int* __restrict__ iw_p,
                                                   float* __restrict__ out) {
    __shared__ int4   s_off[NS];   // float4-row index: cell*(CC/4)
    __shared__ float4 s_wt[NS];
    __shared__ float  tile[NS * TILE_PAD];  // [s][c] c-minor, c in [0,256)

    const int b   = blockIdx.x;
    const int tid = threadIdx.x;
    const int g   = tid & 63;   // float4 channel-group within 256-chunk
    const int sp  = tid >> 6;   // sample phase (wave id)

    if (tid < NS) {
        int4 o; float4 w4;
        box_setup(tid, b, boxes, ih_p, iw_p, &o, &w4);
        o.x *= (CC / 4); o.y *= (CC / 4); o.z *= (CC / 4); o.w *= (CC / 4);
        s_off[tid] = o;
        s_wt[tid]  = w4;
    }
    __syncthreads();

    const size_t outbase = (size_t)b * (CC * NS);

    for (int c0 = 0; c0 < CC; c0 += 256) {
        const float4* src4 = (const float4*)(src + c0);
        // ---- compute phase: lane = 4-channel group, wave = sample phase ----
        for (int s = sp; s < NS; s += 4) {
            int4   o = s_off[s];
            float4 w = s_wt[s];
            float4 a = src4[o.x + g];
            float4 bb = src4[o.y + g];
            float4 c = src4[o.z + g];
            float4 d = src4[o.w + g];
            float4 v;
            v.x = a.x * w.x + bb.x * w.y + c.x * w.z + d.x * w.w;
            v.y = a.y * w.x + bb.y * w.y + c.y * w.z + d.y * w.w;
            v.z = a.z * w.x + bb.z * w.y + c.z * w.z + d.z * w.w;
            v.w = a.w * w.x + bb.w * w.y + c.w * w.z + d.w * w.w;
            *(float4*)(&tile[s * TILE_PAD + 4 * g]) = v;
        }
        __syncthreads();
        // ---- write phase: lane = output order (coalesced float4 NT stores) ----
        float* outc = out + outbase + (size_t)c0 * NS;
#pragma unroll 4
        for (int k4 = tid; k4 < NE4; k4 += 256) {
            int e = k4 * 4;
            int c = e / NS;          // magic-mul, once per float4
            int s = e - c * NS;
            floatv4 v;
            v.x = tile[s * TILE_PAD + c];
            if (++s == NS) { s = 0; ++c; }
            v.y = tile[s * TILE_PAD + c];
            if (++s == NS) { s = 0; ++c; }
            v.z = tile[s * TILE_PAD + c];
            if (++s == NS) { s = 0; ++c; }
            v.w = tile[s * TILE_PAD + c];
            __builtin_nontemporal_store(v, (floatv4*)outc + k4);
        }
        __syncthreads();
    }
}

// Fallback (ws too small for transpose): original scalar path on raw feats.
__global__ __launch_bounds__(256) void roi_pool_fb(const float* __restrict__ src,
                                                   const float* __restrict__ boxes,
                                                   const int* __restrict__ ih_p,
                                                   const int* __restrict__ iw_p,
                                                   float* __restrict__ out) {
    __shared__ int4   s_off[NS];
    __shared__ float4 s_wt[NS];
    __shared__ float  tile[NS * 257];

    const int b   = blockIdx.x;
    const int tid = threadIdx.x;

    if (tid < NS) {
        int4 o; float4 w4;
        box_setup(tid, b, boxes, ih_p, iw_p, &o, &w4);
        s_off[tid] = o;
        s_wt[tid]  = w4;
    }
    __syncthreads();

    const size_t outbase = (size_t)b * (CC * NS);
    for (int c0 = 0; c0 < CC; c0 += 256) {
        const int cterm = (c0 + tid) * (HF * WF);
        for (int s = 0; s < NS; ++s) {
            int4   o = s_off[s];
            float4 w = s_wt[s];
            float v = src[o.x + cterm] * w.x + src[o.y + cterm] * w.y +
                      src[o.z + cterm] * w.z + src[o.w + cterm] * w.w;
            tile[s * 257 + tid] = v;
        }
        __syncthreads();
        const size_t ob = outbase + (size_t)c0 * NS;
        for (int k = tid; k < 256 * NS; k += 256) {
            int cl = k / NS;
            int s  = k - cl * NS;
            out[ob + k] = tile[s * 257 + cl];
        }
        __syncthreads();
    }
}

extern "C" void kernel_launch(void* const* d_in, const int* in_sizes, int n_in,
                              void* d_out, int out_size, void* d_ws, size_t ws_size,
                              hipStream_t stream) {
    const float* feats = (const float*)d_in[0];
    const float* boxes = (const float*)d_in[1];
    const int*   ih    = (const int*)d_in[2];
    const int*   iw    = (const int*)d_in[3];
    float*       out   = (float*)d_out;
    const int B = in_sizes[1] / 4;

    const size_t need = (size_t)CC * HF * WF * sizeof(float);  // 32 MiB
    if (ws_size >= need) {
        float* tf = (float*)d_ws;
        dim3 tb(32, 8);
        dim3 tg((HF * WF) / 32, CC / 32);
        transpose_feats<<<tg, tb, 0, stream>>>(feats, tf);
        roi_pool_v2<<<B, 256, 0, stream>>>(tf, boxes, ih, iw, out);
    } else {
        roi_pool_fb<<<B, 256, 0, stream>>>(feats, boxes, ih, iw, out);
    }
}